// Round 3
// baseline (552.460 us; speedup 1.0000x reference)
//
#include <hip/hip_runtime.h>

typedef unsigned short u16;
typedef __attribute__((ext_vector_type(8))) short short8;   // 8 x bf16 (4 VGPRs)
typedef __attribute__((ext_vector_type(4))) float f32x4;    // MFMA C/D frag

#define DEVI __device__ __forceinline__

DEVI float u2f(u16 u) {
    unsigned int x = ((unsigned int)u) << 16;
    float f; __builtin_memcpy(&f, &x, 4); return f;
}
DEVI u16 f2u(float f) {  // RNE bf16 (finite values)
    unsigned int x; __builtin_memcpy(&x, &f, 4);
    x = (x + 0x7fffu + ((x >> 16) & 1u)) >> 16;
    return (u16)x;
}
// flagged loads: f32 != 0 -> input buffer is float32, convert to bf16
DEVI short8 load8(const void* p, size_t idx, int f32) {
    if (f32) {
        const float* q = (const float*)p + idx;
        short8 r;
#pragma unroll
        for (int j = 0; j < 8; ++j) r[j] = (short)f2u(q[j]);
        return r;
    }
    return *(const short8*)((const u16*)p + idx);
}
DEVI float loadf(const void* p, size_t idx, int f32) {
    return f32 ? ((const float*)p)[idx] : u2f(((const u16*)p)[idx]);
}

// ---------------------------------------------------------------------------
// Dtype sniffer: if Wq is fp32, its u16 stream has ~25% wild exponents
// (uniform mantissa bits); true bf16 Wq (|w| <= ~0.2) has none.  1 block x 64.
__global__ void sniff(const u16* __restrict__ W, int* __restrict__ flag) {
    int wild = 0;
    for (int i = threadIdx.x; i < 4096; i += 64) {
        int e = (W[i] >> 7) & 0xFF;
        if (e >= 0xC0) wild++;
    }
#pragma unroll
    for (int m = 1; m < 64; m <<= 1) wild += __shfl_xor(wild, m);
    if (threadIdx.x == 0) *flag = (wild > 64) ? 1 : 0;
}

// ---------------------------------------------------------------------------
// Weight transpose: WT[n][k] = W[k][n].  W is [K][N] (flagged dtype).
// grid: (N/64, K/64), block 256.
__global__ __launch_bounds__(256) void transpose_k(
    const void* __restrict__ W, u16* __restrict__ WT, int K, int N,
    const int* __restrict__ flagp)
{
    __shared__ u16 T[64 * 72];
    const int f32 = *flagp;
    const int tid = threadIdx.x;
    const int k0 = blockIdx.y * 64, n0 = blockIdx.x * 64;
#pragma unroll
    for (int i = 0; i < 2; ++i) {
        int c = tid + i * 256;              // 0..511
        int row = c >> 3, n8 = (c & 7) * 8; // row: k-local
        short8 v = load8(W, (size_t)(k0 + row) * N + n0 + n8, f32);
#pragma unroll
        for (int j = 0; j < 8; ++j)
            T[(n8 + j) * 72 + row] = (u16)v[j];
    }
    __syncthreads();
#pragma unroll
    for (int i = 0; i < 2; ++i) {
        int c = tid + i * 256;
        int n = c >> 3, k8 = (c & 7) * 8;
        *(short8*)&WT[(size_t)(n0 + n) * K + k0 + k8] = *(const short8*)&T[n * 72 + k8];
    }
}

// ---------------------------------------------------------------------------
// GEMM: C[M][N] = X[M][K] @ WT[N][K]^T  (+ optional residual).
// X flagged-dtype iff a_f; resid flagged-dtype; C written fp32 iff (c_f && f32).
// 128x128 tile, 4 waves (2x2), BK=32. grid (N/128, M/128), block 256.
__global__ __launch_bounds__(256) void gemm_bt(
    const void* __restrict__ X, int lda,
    const u16* __restrict__ WT,
    void* __restrict__ C, int ldc, const void* __restrict__ resid,
    int M, int N, int K, const int* __restrict__ flagp, int a_f, int c_f)
{
    __shared__ u16 As[128 * 40];
    __shared__ u16 Bs[128 * 40];
    const int f32 = *flagp;
    const int af = a_f && f32, cf = c_f && f32;
    const int tid = threadIdx.x;
    const int lane = tid & 63, w = tid >> 6;
    const int wm = w >> 1, wn = w & 1;
    const int l15 = lane & 15, quad = lane >> 4;
    const int m0 = blockIdx.y * 128, n0 = blockIdx.x * 128;

    f32x4 acc[4][4] = {};
    for (int k0 = 0; k0 < K; k0 += 32) {
#pragma unroll
        for (int i = 0; i < 2; ++i) {
            int c = tid + i * 256;           // 0..511
            int row = c >> 2, k8 = (c & 3) * 8;
            *(short8*)&As[row * 40 + k8] = load8(X, (size_t)(m0 + row) * lda + k0 + k8, af);
            *(short8*)&Bs[row * 40 + k8] = *(const short8*)&WT[(size_t)(n0 + row) * K + k0 + k8];
        }
        __syncthreads();
        short8 a[4], b[4];
#pragma unroll
        for (int mt = 0; mt < 4; ++mt)
            a[mt] = *(const short8*)&As[(wm * 64 + mt * 16 + l15) * 40 + quad * 8];
#pragma unroll
        for (int nt = 0; nt < 4; ++nt)
            b[nt] = *(const short8*)&Bs[(wn * 64 + nt * 16 + l15) * 40 + quad * 8];
#pragma unroll
        for (int mt = 0; mt < 4; ++mt)
#pragma unroll
            for (int nt = 0; nt < 4; ++nt)
                acc[mt][nt] = __builtin_amdgcn_mfma_f32_16x16x32_bf16(a[mt], b[nt], acc[mt][nt], 0, 0, 0);
        __syncthreads();
    }
#pragma unroll
    for (int mt = 0; mt < 4; ++mt) {
#pragma unroll
        for (int r = 0; r < 4; ++r) {
            int row = m0 + wm * 64 + mt * 16 + quad * 4 + r;
#pragma unroll
            for (int nt = 0; nt < 4; ++nt) {
                int col = n0 + wn * 64 + nt * 16 + l15;
                float v = acc[mt][nt][r];
                if (resid) v += loadf(resid, (size_t)row * ldc + col, f32);
                if (cf) ((float*)C)[(size_t)row * ldc + col] = v;
                else    ((u16*)C)[(size_t)row * ldc + col] = f2u(v);
            }
        }
    }
}

// ---------------------------------------------------------------------------
// RMSNorm over dim_head=128, in-place on qkv buffer [4096][3072] (bf16).
// One wave per (token, head); heads 0..15 = q, 16..19 = k. grid 20480, block 256.
__global__ __launch_bounds__(256) void rmsnorm_qk(
    u16* __restrict__ qkv, const void* __restrict__ qg, const void* __restrict__ kg,
    const int* __restrict__ flagp)
{
    const int f32 = *flagp;
    const int tid = threadIdx.x, lane = tid & 63, w = tid >> 6;
    const int g = blockIdx.x * 4 + w;        // 0..81919
    const int token = g / 20, head = g % 20;
    const void* gamma; int off;
    if (head < 16) { off = head * 128; gamma = qg; }
    else           { off = 2048 + (head - 16) * 128; gamma = kg; }
    u16* p = qkv + (size_t)token * 3072 + off + lane * 2;
    float f0 = u2f(p[0]), f1 = u2f(p[1]);
    float ss = f0 * f0 + f1 * f1;
#pragma unroll
    for (int m = 1; m < 64; m <<= 1) ss += __shfl_xor(ss, m);
    float r = rsqrtf(ss * (1.0f / 128.0f) + 1e-8f);
    p[0] = f2u(f0 * r * loadf(gamma, lane * 2, f32));
    p[1] = f2u(f1 * r * loadf(gamma, lane * 2 + 1, f32));
}

// ---------------------------------------------------------------------------
// V transpose: vT[(b*4+kvh)*128 + d][s] = qkv[(b*2048+s)][2560 + kvh*128 + d]
// grid (32, 4, 2), block 256.  (all bf16 ws buffers)
__global__ __launch_bounds__(256) void vtrans(
    const u16* __restrict__ qkv, u16* __restrict__ vT)
{
    __shared__ u16 T[128 * 72];
    const int tid = threadIdx.x;
    const int t0 = blockIdx.x * 64;
    const int kvh = blockIdx.y, b = blockIdx.z;
#pragma unroll
    for (int i = 0; i < 4; ++i) {
        int c = tid + i * 256;                // 0..1023
        int tl = c >> 4, d8 = (c & 15) * 8;
        short8 v = *(const short8*)&qkv[(size_t)(b * 2048 + t0 + tl) * 3072 + 2560 + kvh * 128 + d8];
#pragma unroll
        for (int j = 0; j < 8; ++j)
            T[(d8 + j) * 72 + tl] = (u16)v[j];
    }
    __syncthreads();
#pragma unroll
    for (int i = 0; i < 4; ++i) {
        int c = tid + i * 256;
        int d = c >> 3, t8 = (c & 7) * 8;
        *(short8*)&vT[((size_t)(b * 4 + kvh) * 128 + d) * 2048 + t0 + t8] =
            *(const short8*)&T[d * 72 + t8];
    }
}

// ---------------------------------------------------------------------------
// Flash attention, causal, GQA. 64 q-rows per block, 64-kv tiles, DH=128.
// Each wave owns 16 q-rows. O written in-place over the Q slice of qkv.
// grid (32, 16, 2) = (qtile, head, batch), block 256.
__global__ __launch_bounds__(256) void attn(
    u16* __restrict__ qkv, const u16* __restrict__ vT)
{
    __shared__ u16 Qs[64 * 136];
    __shared__ u16 Ks[64 * 136];
    __shared__ u16 Vs[128 * 72];
    __shared__ u16 Ps[64 * 72];
    const int tid = threadIdx.x, lane = tid & 63, w = tid >> 6;
    const int l15 = lane & 15, quad = lane >> 4;
    const int qt = blockIdx.x, h = blockIdx.y, b = blockIdx.z;
    const int kvh = h >> 2;
    const int q0 = qt * 64;
    const float scale = 0.08838834764831845f;

#pragma unroll
    for (int i = 0; i < 4; ++i) {
        int c = tid + i * 256;
        int r = c >> 4, d8 = (c & 15) * 8;
        *(short8*)&Qs[r * 136 + d8] =
            *(const short8*)&qkv[(size_t)(b * 2048 + q0 + r) * 3072 + h * 128 + d8];
    }
    __syncthreads();
    short8 qf[4];
#pragma unroll
    for (int ks = 0; ks < 4; ++ks)
        qf[ks] = *(const short8*)&Qs[(w * 16 + l15) * 136 + ks * 32 + quad * 8];

    f32x4 o[8] = {};
    float mrow[4], lrow[4];
#pragma unroll
    for (int r = 0; r < 4; ++r) { mrow[r] = -1e30f; lrow[r] = 0.f; }

    for (int kt = 0; kt <= qt; ++kt) {
        const int kv0 = kt * 64;
#pragma unroll
        for (int i = 0; i < 4; ++i) {
            int c = tid + i * 256;
            int r = c >> 4, d8 = (c & 15) * 8;
            *(short8*)&Ks[r * 136 + d8] =
                *(const short8*)&qkv[(size_t)(b * 2048 + kv0 + r) * 3072 + 2048 + kvh * 128 + d8];
        }
#pragma unroll
        for (int i = 0; i < 4; ++i) {
            int c = tid + i * 256;
            int d = c >> 3, t8 = (c & 7) * 8;
            *(short8*)&Vs[d * 72 + t8] =
                *(const short8*)&vT[((size_t)(b * 4 + kvh) * 128 + d) * 2048 + kv0 + t8];
        }
        __syncthreads();

        // S = Q K^T  (each wave: 16 q-rows x 64 kv-cols)
        f32x4 s[4];
#pragma unroll
        for (int nt = 0; nt < 4; ++nt) {
            f32x4 a = {};
#pragma unroll
            for (int ks = 0; ks < 4; ++ks) {
                short8 bk = *(const short8*)&Ks[(nt * 16 + l15) * 136 + ks * 32 + quad * 8];
                a = __builtin_amdgcn_mfma_f32_16x16x32_bf16(qf[ks], bk, a, 0, 0, 0);
            }
            s[nt] = a;
        }
        const bool diag = (kt == qt);
#pragma unroll
        for (int nt = 0; nt < 4; ++nt) {
            int col = nt * 16 + l15;
#pragma unroll
            for (int r = 0; r < 4; ++r) {
                float v = s[nt][r] * scale;
                if (diag) {
                    int row = w * 16 + quad * 4 + r;
                    if (col > row) v = -1e30f;
                }
                s[nt][r] = v;
            }
        }
        // online softmax
        float alpha[4];
#pragma unroll
        for (int r = 0; r < 4; ++r) {
            float mx = s[0][r];
#pragma unroll
            for (int nt = 1; nt < 4; ++nt) mx = fmaxf(mx, s[nt][r]);
#pragma unroll
            for (int msk = 1; msk < 16; msk <<= 1) mx = fmaxf(mx, __shfl_xor(mx, msk));
            float mn = fmaxf(mrow[r], mx);
            alpha[r] = __expf(mrow[r] - mn);
            mrow[r] = mn;
        }
#pragma unroll
        for (int r = 0; r < 4; ++r) {
            float sum = 0.f;
#pragma unroll
            for (int nt = 0; nt < 4; ++nt) {
                float p = __expf(s[nt][r] - mrow[r]);
                s[nt][r] = p;
                sum += p;
            }
#pragma unroll
            for (int msk = 1; msk < 16; msk <<= 1) sum += __shfl_xor(sum, msk);
            lrow[r] = lrow[r] * alpha[r] + sum;
        }
#pragma unroll
        for (int nt = 0; nt < 4; ++nt)
#pragma unroll
            for (int r = 0; r < 4; ++r)
                Ps[(w * 16 + quad * 4 + r) * 72 + nt * 16 + l15] = f2u(s[nt][r]);
#pragma unroll
        for (int nto = 0; nto < 8; ++nto)
#pragma unroll
            for (int r = 0; r < 4; ++r)
                o[nto][r] *= alpha[r];
        __syncthreads();

        // O += P @ V
        short8 pa[2];
#pragma unroll
        for (int ks = 0; ks < 2; ++ks)
            pa[ks] = *(const short8*)&Ps[(w * 16 + l15) * 72 + ks * 32 + quad * 8];
#pragma unroll
        for (int nto = 0; nto < 8; ++nto) {
#pragma unroll
            for (int ks = 0; ks < 2; ++ks) {
                short8 bv = *(const short8*)&Vs[(nto * 16 + l15) * 72 + ks * 32 + quad * 8];
                o[nto] = __builtin_amdgcn_mfma_f32_16x16x32_bf16(pa[ks], bv, o[nto], 0, 0, 0);
            }
        }
        __syncthreads();
    }
    // write O in-place over the Q slice (row stride 3072)
#pragma unroll
    for (int r = 0; r < 4; ++r) {
        float inv = 1.0f / lrow[r];
        int row = q0 + w * 16 + quad * 4 + r;
#pragma unroll
        for (int nto = 0; nto < 8; ++nto)
            qkv[(size_t)(b * 2048 + row) * 3072 + h * 128 + nto * 16 + l15] =
                f2u(o[nto][r] * inv);
    }
}

// ---------------------------------------------------------------------------
// Workspace layout (peak ~44 MiB + flag word):
//   [0,         8388608)  WoT   [2048][2048]   live until final GEMM
//   [8388608,  33554432)  QKV   [4096][3072]   q-slice becomes O in-place
//   [33554432, 37748736)  vT    [8][128][2048] written AFTER WTqkv is dead
//   [33554432, 46137344)  WTqkv [3072][2048]   dead after QKV GEMM
//   [46137344, 46137348)  dtype flag (int)
extern "C" void kernel_launch(void* const* d_in, const int* in_sizes, int n_in,
                              void* d_out, int out_size, void* d_ws, size_t ws_size,
                              hipStream_t stream) {
    const void* x  = d_in[0];   // [2,2048,2048]
    const void* Wq = d_in[1];   // [2048,2048]
    const void* Wk = d_in[2];   // [2048,512]
    const void* Wv = d_in[3];   // [2048,512]
    const void* Wo = d_in[4];   // [2048,2048]
    const void* qg = d_in[5];   // [128]
    const void* kg = d_in[6];   // [128]

    char* ws = (char*)d_ws;
    u16* WoT   = (u16*)(ws);
    u16* QKV   = (u16*)(ws + 8388608);
    u16* vT    = (u16*)(ws + 33554432);
    u16* WTqkv = (u16*)(ws + 33554432);
    int* flag  = (int*)(ws + 46137344);

    // 0. detect input dtype (fp32 vs bf16) from Wq's bit patterns
    sniff<<<1, 64, 0, stream>>>((const u16*)Wq, flag);

    // 1. transpose weights into K-inner bf16 layout
    transpose_k<<<dim3(32, 32), 256, 0, stream>>>(Wo, WoT, 2048, 2048, flag);
    transpose_k<<<dim3(32, 32), 256, 0, stream>>>(Wq, WTqkv, 2048, 2048, flag);
    transpose_k<<<dim3(8, 32), 256, 0, stream>>>(Wk, WTqkv + (size_t)2048 * 2048, 2048, 512, flag);
    transpose_k<<<dim3(8, 32), 256, 0, stream>>>(Wv, WTqkv + (size_t)2560 * 2048, 2048, 512, flag);

    // 2. QKV projection: [4096][2048] @ -> [4096][3072]  (A = x, flagged)
    gemm_bt<<<dim3(24, 32), 256, 0, stream>>>(x, 2048, WTqkv, QKV, 3072, nullptr,
                                              4096, 3072, 2048, flag, 1, 0);

    // 3. RMSNorm on q,k heads; V transpose (WTqkv now dead; vT overlays it)
    rmsnorm_qk<<<dim3(20480), 256, 0, stream>>>(QKV, qg, kg, flag);
    vtrans<<<dim3(32, 4, 2), 256, 0, stream>>>(QKV, vT);

    // 4. causal GQA flash attention, O written in-place into QKV's q-slice
    attn<<<dim3(32, 16, 2), 256, 0, stream>>>(QKV, vT);

    // 5. output projection + residual (resid = x flagged, C = d_out flagged)
    gemm_bt<<<dim3(16, 32), 256, 0, stream>>>(QKV, 3072, WoT, d_out, 2048, x,
                                              4096, 2048, 2048, flag, 0, 1);
}